// Round 18
// baseline (25.351 us; speedup 1.0000x reference)
//
#include <hip/hip_runtime.h>
#include <hip/hip_bf16.h>

#define VOCAB 32000
#define EDIM  128
#define QN    32
#define DN    256
#define NK    11

typedef __attribute__((ext_vector_type(8))) short bf16x8;
typedef __attribute__((ext_vector_type(4))) float f32x4;

#define EXP2F(x) __builtin_amdgcn_exp2f(x)

// RNE float -> bf16
static __device__ inline unsigned short f2bf(float f) {
    unsigned u = __float_as_uint(f);
    return (unsigned short)((u + 0x7fff + ((u >> 16) & 1)) >> 16);
}

// ---------------- pre-pass: L2-normalize rows + bf16 table (streaming, BW-bound) ----------------
__global__ __launch_bounds__(256) void norm_bf16_kernel(const float* __restrict__ emb,
                                                        unsigned int* __restrict__ nbf) {
    int lane = threadIdx.x & 63;
    int row  = blockIdx.x * 4 + (threadIdx.x >> 6);
    const float2* p = (const float2*)(emb + (size_t)row * EDIM);
    float2 v = p[lane];
    float s = v.x * v.x + v.y * v.y;
    #pragma unroll
    for (int off = 32; off; off >>= 1) s += __shfl_xor(s, off);
    float inv = 1.0f / sqrtf(s);
    unsigned int packed = ((unsigned)f2bf(v.y * inv) << 16) | f2bf(v.x * inv);
    nbf[(size_t)row * (EDIM / 2) + lane] = packed;
}

template <int CTRL>
static __device__ inline float dpp_add(float x) {
    int y = __builtin_amdgcn_update_dpp(0, __float_as_int(x), CTRL, 0xF, 0xF, true);
    return x + __int_as_float(y);
}

static __device__ inline int swz(int r, int c) { return c ^ ((r & 7) << 4); }

// ---------------- main: one 8-wave block per batch; bf16-table gathers ----------------
__global__ __launch_bounds__(512, 4) void knrm_main(const int* __restrict__ qtok,
                                                    const int* __restrict__ dtok,
                                                    const unsigned short* __restrict__ nbf,
                                                    const float* __restrict__ fcw,
                                                    float* __restrict__ out) {
    __shared__ __align__(16) unsigned short dbuf[DN * EDIM];  // 64 KB; part4 overlay after eval
    __shared__ __align__(16) unsigned short qbuf[QN * EDIM];  // 8 KB
    __shared__ float redS[8];

    const float C0 = 0.3989422804014327f;
    const float C1 = 7.30620157e-3f;
    const float C2 = 2.45119242e-6f;
    const float C3 = 1.50605972e-11f;
    const float C4 = 1.69484929e-18f;

    int b = blockIdx.x, tid = threadIdx.x;
    int w = tid >> 6, lane = tid & 63;
    int lr = lane & 15, lg = lane >> 4;
    int qt = w & 1, ds = w >> 1;

    const int* qtb = qtok + b * QN;
    const int* dtb = dtok + b * DN;

    // ---- all token loads up front ----
    int tq = qtb[(w << 2) + lg];
    int tdr[8];
    #pragma unroll
    for (int it = 0; it < 8; ++it) tdr[it] = dtb[(w << 5) + (it << 2) + lg];
    int tcurs[4], qtr[4];
    #pragma unroll
    for (int t = 0; t < 4; ++t) tcurs[t] = dtb[(t << 6) + (ds << 4) + lr];
    #pragma unroll
    for (int r = 0; r < 4; ++r) qtr[r] = qtb[(qt << 4) + (lg << 2) + r];

    // ---- 9 bf16 row gathers, 16B/lane (36 VGPRs in flight - true upfront MLP) ----
    bf16x8 qv = *(const bf16x8*)(nbf + (size_t)tq * EDIM + lr * 8);
    bf16x8 dv[8];
    #pragma unroll
    for (int it = 0; it < 8; ++it)
        dv[it] = *(const bf16x8*)(nbf + (size_t)tdr[it] * EDIM + lr * 8);

    // ---- stage to swizzled LDS (no VALU processing needed) ----
    {
        int qr = (w << 2) + lg;
        *(bf16x8*)((char*)qbuf + qr * 256 + swz(qr, lr * 16)) = qv;
    }
    #pragma unroll
    for (int it = 0; it < 8; ++it) {
        int r = (w << 5) + (it << 2) + lg;
        *(bf16x8*)((char*)dbuf + r * 256 + swz(r, lr * 16)) = dv[it];
    }
    __syncthreads();                                  // bar1: all LDS staged

    // ---- A fragments ----
    bf16x8 A0, A1, A2, A3;
    {
        int qr = (qt << 4) + lr;
        const char* qb = (const char*)qbuf + qr * 256;
        A0 = *(const bf16x8*)(qb + swz(qr, lg * 16));
        A1 = *(const bf16x8*)(qb + swz(qr, lg * 16 + 64));
        A2 = *(const bf16x8*)(qb + swz(qr, lg * 16 + 128));
        A3 = *(const bf16x8*)(qb + swz(qr, lg * 16 + 192));
    }

    float kacc[4][NK];
    #pragma unroll
    for (int r = 0; r < 4; ++r)
        #pragma unroll
        for (int k = 0; k < NK; ++k) kacc[r][k] = 0.0f;

    #pragma unroll
    for (int t = 0; t < 4; ++t) {
        int dr = (t << 6) + (ds << 4) + lr;
        const char* db = (const char*)dbuf + dr * 256;
        bf16x8 B0 = *(const bf16x8*)(db + swz(dr, lg * 16));
        bf16x8 B1 = *(const bf16x8*)(db + swz(dr, lg * 16 + 64));
        bf16x8 B2 = *(const bf16x8*)(db + swz(dr, lg * 16 + 128));
        bf16x8 B3 = *(const bf16x8*)(db + swz(dr, lg * 16 + 192));
        int tcur = tcurs[t];

        f32x4 acc = {0.0f, 0.0f, 0.0f, 0.0f};
        acc = __builtin_amdgcn_mfma_f32_16x16x32_bf16(A0, B0, acc, 0, 0, 0);
        acc = __builtin_amdgcn_mfma_f32_16x16x32_bf16(A1, B1, acc, 0, 0, 0);
        acc = __builtin_amdgcn_mfma_f32_16x16x32_bf16(A2, B2, acc, 0, 0, 0);
        acc = __builtin_amdgcn_mfma_f32_16x16x32_bf16(A3, B3, acc, 0, 0, 0);

        bool dok = (tcur > 0);
        float mc = dok ? C0 : 0.0f;
        #pragma unroll
        for (int r = 0; r < 4; ++r) {
            float t2 = acc[r];                            // rows pre-normalized
            kacc[r][0] += (tcur == qtr[r]) ? mc : 0.0f;   // K0: exact token match
            float d  = t2 - 0.1f;
            float g  = EXP2F(d * d * -72.1347520f);       // K5 shape
            g = dok ? g : 0.0f;
            float Em = EXP2F(t2 * -28.8539008f);
            float Ep = EXP2F(t2 *  28.8539008f);
            float h = g;
            kacc[r][5]  += h * C0;
            h *= Em; kacc[r][6]  += h * C0;
            h *= Em; kacc[r][7]  += h * C1;
            h *= Em; kacc[r][8]  += h * C2;
            h *= Em; kacc[r][9]  += h * C3;
            h *= Em; kacc[r][10] += h * C4;
            h = g;
            h *= Ep; kacc[r][4]  += h * C1;
            h *= Ep; kacc[r][3]  += h * C2;
            h *= Ep; kacc[r][2]  += h * C3;
            h *= Ep; kacc[r][1]  += h * C4;
        }
    }
    __syncthreads();                                  // bar2: all dbuf B-reads done

    // ---- cheap reduction: 2 DPP steps (quad sums) + quad-leader writes [.. ][48] ----
    #pragma unroll
    for (int r = 0; r < 4; ++r)
        #pragma unroll
        for (int k = 0; k < NK; ++k) {
            float x = kacc[r][k];
            x = dpp_add<0xB1>(x);                     // xor 1
            x = dpp_add<0x4E>(x);                     // xor 2 -> quad sum
            kacc[r][k] = x;
        }
    float* part4 = (float*)dbuf;                      // [8w][4lg][4quad][48] = 24.6 KB
    if ((lr & 3) == 0) {
        int quad = lr >> 2;
        float* pw = part4 + (((w << 2) + lg) * 4 + quad) * 48;
        float flat[44];
        #pragma unroll
        for (int r = 0; r < 4; ++r)
            #pragma unroll
            for (int k = 0; k < NK; ++k) flat[r * NK + k] = kacc[r][k];
        #pragma unroll
        for (int j = 0; j < 11; ++j) {
            float4 v = {flat[j * 4], flat[j * 4 + 1], flat[j * 4 + 2], flat[j * 4 + 3]};
            *(float4*)(pw + j * 4) = v;
        }
    }
    __syncthreads();                                  // bar3: part4 visible

    // ---- combine 4 dspans x 4 quads, log-pool, weighted sum -> out[b] ----
    float total = 0.0f;
    if (tid < QN * NK) {
        int q = tid / NK, k = tid - (tid / NK) * NK;
        int qt2 = q >> 4, row = q & 15;
        int lg2 = row >> 2, r = row & 3;
        float v = 0.0f;
        #pragma unroll
        for (int d2 = 0; d2 < 4; ++d2)
            #pragma unroll
            for (int qd = 0; qd < 4; ++qd)
                v += part4[((((d2 * 2 + qt2) << 2) + lg2) * 4 + qd) * 48 + r * NK + k];
        float m = (qtb[q] > 0) ? 1.0f : 0.0f;
        total = m * fcw[k] * __logf(fmaxf(v, 1e-10f));
    }
    #pragma unroll
    for (int off = 32; off; off >>= 1) total += __shfl_xor(total, off);
    if (lane == 0) redS[w] = total;
    __syncthreads();                                  // bar4
    if (tid == 0) {
        float s = 0.0f;
        #pragma unroll
        for (int i = 0; i < 8; ++i) s += redS[i];
        out[b] = s;
    }
}

extern "C" void kernel_launch(void* const* d_in, const int* in_sizes, int n_in,
                              void* d_out, int out_size, void* d_ws, size_t ws_size,
                              hipStream_t stream) {
    const int*   qtok = (const int*)d_in[0];
    const int*   dtok = (const int*)d_in[1];
    const float* emb  = (const float*)d_in[2];
    const float* fcw  = (const float*)d_in[3];
    float* out = (float*)d_out;
    unsigned int* nbf = (unsigned int*)d_ws;   // 32000*128 bf16 = 8.192 MB

    norm_bf16_kernel<<<VOCAB / 4, 256, 0, stream>>>(emb, nbf);

    int B = in_sizes[0] / QN;                  // 512
    knrm_main<<<B, 512, 0, stream>>>(qtok, dtok, (const unsigned short*)nbf, fcw, out);
}

// Round 19
// 21.255 us; speedup vs baseline: 1.1927x; 1.1927x over previous
//
#include <hip/hip_runtime.h>
#include <hip/hip_bf16.h>

#define EDIM  128
#define QN    32
#define DN    256
#define NK    11

typedef __attribute__((ext_vector_type(8))) short bf16x8;
typedef __attribute__((ext_vector_type(4))) float f32x4;

#define EXP2F(x) __builtin_amdgcn_exp2f(x)

// ---- DPP 16-lane sum (within each aligned group of 16 lanes) ----
template <int CTRL>
static __device__ inline float dpp_add(float x) {
    int y = __builtin_amdgcn_update_dpp(0, __float_as_int(x), CTRL, 0xF, 0xF, true);
    return x + __int_as_float(y);
}
static __device__ inline float sum16(float x) {
    x = dpp_add<0xB1>(x);    // quad_perm xor 1
    x = dpp_add<0x4E>(x);    // quad_perm xor 2
    x = dpp_add<0x124>(x);   // row_ror:4
    x = dpp_add<0x128>(x);   // row_ror:8
    return x;
}

// XOR row swizzle within a 256B bf16 row
static __device__ inline int swz(int r, int c) { return c ^ ((r & 7) << 4); }

static __device__ inline bf16x8 pack8(float4 a, float4 b) {
    union { bf16x8 v; __hip_bfloat16 h[8]; } u;
    u.h[0] = __float2bfloat16(a.x); u.h[1] = __float2bfloat16(a.y);
    u.h[2] = __float2bfloat16(a.z); u.h[3] = __float2bfloat16(a.w);
    u.h[4] = __float2bfloat16(b.x); u.h[5] = __float2bfloat16(b.y);
    u.h[6] = __float2bfloat16(b.z); u.h[7] = __float2bfloat16(b.w);
    return u.v;
}
static __device__ inline float sumsq8(float4 a, float4 b) {
    float s = a.x * a.x + a.y * a.y + a.z * a.z + a.w * a.w;
    s = fmaf(b.x, b.x, s); s = fmaf(b.y, b.y, s);
    s = fmaf(b.z, b.z, s); s = fmaf(b.w, b.w, s);
    return s;
}

// ---------------- fused kernel: one 8-wave block per batch (R12 structure) ----------------
// Split-staged d rows: [0,128) before bar1, [128,256) overlapped with eval tiles 0,1.
// Tile t of wave (qt,ds) covers doc rows t*64 + ds*16 + lr  (t=0,1 entirely in half 1).
__global__ __launch_bounds__(512, 4) void knrm_fused(const int* __restrict__ qtok,
                                                     const int* __restrict__ dtok,
                                                     const float* __restrict__ emb,
                                                     const float* __restrict__ fcw,
                                                     float* __restrict__ out) {
    __shared__ __align__(16) unsigned short dbuf[DN * EDIM];  // 64 KB
    __shared__ __align__(16) unsigned short qbuf[QN * EDIM];  // 8 KB; overlaid by part[8][16][NK]
    __shared__ int   dtokS[DN];
    __shared__ int   qtokS[QN];
    __shared__ float invS[DN + QN];
    __shared__ float redS[8];

    // chain literals: Cj = inv_sqrt_2pi * e^{-4*T(j)}, T = 0,4,12,24,40 cumulative
    const float C0 = 0.3989422804014327f;
    const float C1 = 7.30620157e-3f;
    const float C2 = 2.45119242e-6f;
    const float C3 = 1.50605972e-11f;
    const float C4 = 1.69484929e-18f;

    int b = blockIdx.x, tid = threadIdx.x;
    int w = tid >> 6, lane = tid & 63;
    int lr = lane & 15, lg = lane >> 4;

    if (tid < DN) dtokS[tid] = dtok[b * DN + tid];
    else if (tid < DN + QN) qtokS[tid - DN] = qtok[b * QN + (tid - DN)];
    __syncthreads();                                  // bar0

    // ---- phase A: stage q rows (32) + d rows [0,128); 16 lanes x 32B per row ----
    {
        int qr = (w << 2) + lg;
        int tok = qtokS[qr];
        const float4* src = (const float4*)(emb + (size_t)tok * EDIM) + lr * 2;
        float4 v0 = src[0], v1 = src[1];
        float tot = sum16(sumsq8(v0, v1));
        if (lr == 0) invS[DN + qr] = 1.0f / sqrtf(tot);
        *(bf16x8*)((char*)qbuf + qr * 256 + swz(qr, lr * 16)) = pack8(v0, v1);
    }
    #pragma unroll
    for (int it = 0; it < 4; ++it) {
        int r = (w << 4) + (it << 2) + lg;            // rows [16w, 16w+16)
        int tok = dtokS[r];
        const float4* src = (const float4*)(emb + (size_t)tok * EDIM) + lr * 2;
        float4 v0 = src[0], v1 = src[1];
        float tot = sum16(sumsq8(v0, v1));
        if (lr == 0) invS[r] = 1.0f / sqrtf(tot);
        *(bf16x8*)((char*)dbuf + r * 256 + swz(r, lr * 16)) = pack8(v0, v1);
    }
    __syncthreads();                                  // bar1: half 1 + q ready

    int qt = w & 1, ds = w >> 1;

    // ---- A fragments + per-row q data (reads of half-1 LDS) ----
    bf16x8 A0, A1, A2, A3;
    {
        int qr = (qt << 4) + lr;
        const char* qb = (const char*)qbuf + qr * 256;
        A0 = *(const bf16x8*)(qb + swz(qr, lg * 16));
        A1 = *(const bf16x8*)(qb + swz(qr, lg * 16 + 64));
        A2 = *(const bf16x8*)(qb + swz(qr, lg * 16 + 128));
        A3 = *(const bf16x8*)(qb + swz(qr, lg * 16 + 192));
    }
    int   qtr[4];
    float invq[4];
    #pragma unroll
    for (int r = 0; r < 4; ++r) {
        int qrow = (qt << 4) + (lg << 2) + r;
        qtr[r]  = qtokS[qrow];
        invq[r] = invS[DN + qrow];
    }

    float kacc[4][NK];
    #pragma unroll
    for (int r = 0; r < 4; ++r)
        #pragma unroll
        for (int k = 0; k < NK; ++k) kacc[r][k] = 0.0f;

    // ---- eval one 16x16 tile: doc rows t*64 + ds*16 + lr ----
    auto evalTile = [&](int t) {
        int dr = (t << 6) + (ds << 4) + lr;
        const char* db = (const char*)dbuf + dr * 256;
        bf16x8 B0 = *(const bf16x8*)(db + swz(dr, lg * 16));
        bf16x8 B1 = *(const bf16x8*)(db + swz(dr, lg * 16 + 64));
        bf16x8 B2 = *(const bf16x8*)(db + swz(dr, lg * 16 + 128));
        bf16x8 B3 = *(const bf16x8*)(db + swz(dr, lg * 16 + 192));
        int   tcur = dtokS[dr];
        float invd = invS[dr];

        f32x4 acc = {0.0f, 0.0f, 0.0f, 0.0f};
        acc = __builtin_amdgcn_mfma_f32_16x16x32_bf16(A0, B0, acc, 0, 0, 0);
        acc = __builtin_amdgcn_mfma_f32_16x16x32_bf16(A1, B1, acc, 0, 0, 0);
        acc = __builtin_amdgcn_mfma_f32_16x16x32_bf16(A2, B2, acc, 0, 0, 0);
        acc = __builtin_amdgcn_mfma_f32_16x16x32_bf16(A3, B3, acc, 0, 0, 0);

        bool dok = (tcur > 0);
        float mc = dok ? C0 : 0.0f;                   // K0 literal, d-masked
        #pragma unroll
        for (int r = 0; r < 4; ++r) {
            float t2 = acc[r] * (invq[r] * invd);
            kacc[r][0] += (tcur == qtr[r]) ? mc : 0.0f;   // K0: exact token match
            float d  = t2 - 0.1f;
            float g  = EXP2F(d * d * -72.1347520f);       // exp(-50(t-0.1)^2)
            g = dok ? g : 0.0f;                           // d-mask folded into chain head
            float Em = EXP2F(t2 * -28.8539008f);          // e^{-20t}
            float Ep = EXP2F(t2 *  28.8539008f);          // e^{+20t}
            float h = g;
            kacc[r][5]  += h * C0;
            h *= Em; kacc[r][6]  += h * C0;
            h *= Em; kacc[r][7]  += h * C1;
            h *= Em; kacc[r][8]  += h * C2;
            h *= Em; kacc[r][9]  += h * C3;
            h *= Em; kacc[r][10] += h * C4;
            h = g;
            h *= Ep; kacc[r][4]  += h * C1;
            h *= Ep; kacc[r][3]  += h * C2;
            h *= Ep; kacc[r][2]  += h * C3;
            h *= Ep; kacc[r][1]  += h * C4;
        }
    };

    // ---- phase B: stage d rows [128,256) ; its gather latency overlaps eval t0,t1 ----
    #pragma unroll
    for (int it = 0; it < 4; ++it) {
        int r = 128 + (w << 4) + (it << 2) + lg;
        int tok = dtokS[r];
        const float4* src = (const float4*)(emb + (size_t)tok * EDIM) + lr * 2;
        float4 v0 = src[0], v1 = src[1];
        float tot = sum16(sumsq8(v0, v1));
        if (lr == 0) invS[r] = 1.0f / sqrtf(tot);
        *(bf16x8*)((char*)dbuf + r * 256 + swz(r, lr * 16)) = pack8(v0, v1);
    }
    evalTile(0);
    evalTile(1);
    __syncthreads();                                  // bar2: half 2 ready

    evalTile(2);
    evalTile(3);

    // ---- DPP reduce over the 16 doc-columns; write partial [16][NK] onto qbuf ----
    #pragma unroll
    for (int r = 0; r < 4; ++r)
        #pragma unroll
        for (int k = 0; k < NK; ++k) kacc[r][k] = sum16(kacc[r][k]);

    float* part = (float*)qbuf;                       // safe: qbuf last read before bar2
    if (lr == 0) {
        float* pw = part + w * (16 * NK) + (lg * 4) * NK;
        #pragma unroll
        for (int r = 0; r < 4; ++r)
            #pragma unroll
            for (int k = 0; k < NK; ++k)
                pw[r * NK + k] = kacc[r][k];
    }
    __syncthreads();                                  // bar3: partials visible

    // ---- combine 4 dspans, log-pool, weighted sum -> out[b] ----
    float total = 0.0f;
    if (tid < QN * NK) {
        int q = tid / NK, k = tid - (tid / NK) * NK;
        int qt2 = q >> 4, row = q & 15;
        const float* pb = part + qt2 * (16 * NK) + row * NK + k;
        float v = pb[0] + pb[2 * 16 * NK] + pb[4 * 16 * NK] + pb[6 * 16 * NK];
        float m = (qtokS[q] > 0) ? 1.0f : 0.0f;
        total = m * fcw[k] * __logf(fmaxf(v, 1e-10f));
    }
    #pragma unroll
    for (int off = 32; off; off >>= 1) total += __shfl_xor(total, off);
    if (lane == 0) redS[w] = total;
    __syncthreads();                                  // bar4
    if (tid == 0) {
        float s = 0.0f;
        #pragma unroll
        for (int i = 0; i < 8; ++i) s += redS[i];
        out[b] = s;
    }
}

extern "C" void kernel_launch(void* const* d_in, const int* in_sizes, int n_in,
                              void* d_out, int out_size, void* d_ws, size_t ws_size,
                              hipStream_t stream) {
    const int*   qtok = (const int*)d_in[0];
    const int*   dtok = (const int*)d_in[1];
    const float* emb  = (const float*)d_in[2];
    const float* fcw  = (const float*)d_in[3];
    float* out = (float*)d_out;

    int B = in_sizes[0] / QN;                  // 512
    knrm_fused<<<B, 512, 0, stream>>>(qtok, dtok, emb, fcw, out);
}